// Round 7
// baseline (720.581 us; speedup 1.0000x reference)
//
#include <hip/hip_runtime.h>

// GATv2 2-layer GNN, MI355X. Inputs/out fp32 (proven r3); compute bf16.
// Round-7: (1) agg2 epilogue atomically accumulates into pooled[G,128]
// (h2 buffer + 51MB round-trip + gcnt-scan deleted; b2 folded into
// poolfinal). (2) poolfinal now reads 256KB. (3) converts fused into one
// dispatch. agg1/gemm/CSR unchanged (r6-proven).

#define DIN 128
#define F1 256   // H*DH layer 1
#define F2 128   // DOUT
#define NEG_SLOPE 0.2f

typedef unsigned short u16;
typedef __attribute__((ext_vector_type(8))) short short8;
typedef __attribute__((ext_vector_type(4))) float floatx4;

__device__ __forceinline__ float bf2f(u16 u) {
  return __uint_as_float(((unsigned int)u) << 16);
}
__device__ __forceinline__ u16 f2bf(float f) {   // round-to-nearest-even
  unsigned int x = __float_as_uint(f);
  return (u16)((x + 0x7fffu + ((x >> 16) & 1u)) >> 16);
}
__device__ __forceinline__ void load8(const u16* p, float (&f)[8]) {
  short8 v = *(const short8*)p;
#pragma unroll
  for (int k = 0; k < 8; k++) f[k] = bf2f((u16)v[k]);
}

// ---------------- dtype detection (flag=1: fp32 inputs; 0: bf16) ----------------
__global__ void k_detect(const u16* __restrict__ x, int* __restrict__ flag) {
  int lane = threadIdx.x;   // 1 block x 64 threads
  int cnt = 0;
#pragma unroll
  for (int i = 0; i < 2; ++i) {
    u16 v = x[2 * (lane + 64 * i)];
    int e = (v >> 7) & 0xFF;
    if (e >= 115 && e <= 130) cnt++;
  }
#pragma unroll
  for (int m = 1; m <= 32; m <<= 1) cnt += __shfl_xor(cnt, m, 64);
  if (lane == 0) *flag = (cnt < 64) ? 1 : 0;
}

// fused convert: blocks [0,nxb) do x (4 elems/thread); rest do params (1/thread)
struct PTab { const void* src[12]; int off[13]; };
__global__ void k_convert_all(const void* __restrict__ xsrc, u16* __restrict__ xb,
                              int n4, int nxb, PTab t, u16* __restrict__ pb,
                              int ptotal, const int* __restrict__ flag) {
  if ((int)blockIdx.x < nxb) {
    int i = blockIdx.x * 256 + threadIdx.x;
    if (i >= n4) return;
    if (*flag) {
      float4 a = ((const float4*)xsrc)[i];
      ushort4 o;
      o.x = f2bf(a.x); o.y = f2bf(a.y); o.z = f2bf(a.z); o.w = f2bf(a.w);
      ((ushort4*)xb)[i] = o;
    } else {
      ((ulong1*)xb)[i] = ((const ulong1*)xsrc)[i];
    }
  } else {
    int i = (blockIdx.x - nxb) * 256 + threadIdx.x;
    if (i >= ptotal) return;
    int s = 0;
#pragma unroll
    for (int k = 1; k < 12; k++) s += (i >= t.off[k]);
    int local = i - t.off[s];
    const void* sp = t.src[s];
    pb[i] = (*flag) ? f2bf(((const float*)sp)[local]) : ((const u16*)sp)[local];
  }
}

// ---------------- CSR build ----------------
__global__ void k_hist(const int* __restrict__ ei, int* __restrict__ hist,
                       const int* __restrict__ batch, int* __restrict__ gcnt,
                       int E, int Etot, int N) {
  int e = blockIdx.x * 256 + threadIdx.x;
  if (e >= Etot) return;
  int dst = (e < E) ? ei[E + e] : (e - E);
  atomicAdd(&hist[dst], 1);
  if (e < N) atomicAdd(&gcnt[batch[e]], 1);
}

__global__ void k_scan1(const int* __restrict__ in, int* __restrict__ out,
                        int* __restrict__ partials, int n) {
  __shared__ int tmp[256];
  int t = threadIdx.x;
  int gid = blockIdx.x * 256 + t;
  int v = (gid < n) ? in[gid] : 0;
  tmp[t] = v;
  __syncthreads();
  for (int off = 1; off < 256; off <<= 1) {
    int add = (t >= off) ? tmp[t - off] : 0;
    __syncthreads();
    tmp[t] += add;
    __syncthreads();
  }
  if (gid < n) out[gid] = tmp[t] - v;
  if (t == 255) partials[blockIdx.x] = tmp[255];
}

__global__ void k_scan2(int* __restrict__ partials, int nb) {
  __shared__ int tmp[256];
  __shared__ int carry_s;
  int t = threadIdx.x;
  if (t == 0) carry_s = 0;
  __syncthreads();
  for (int base = 0; base < nb; base += 256) {
    int idx = base + t;
    int v = (idx < nb) ? partials[idx] : 0;
    tmp[t] = v;
    __syncthreads();
    for (int off = 1; off < 256; off <<= 1) {
      int add = (t >= off) ? tmp[t - off] : 0;
      __syncthreads();
      tmp[t] += add;
      __syncthreads();
    }
    int carry = carry_s;
    if (idx < nb) partials[idx] = tmp[t] - v + carry;
    __syncthreads();
    if (t == 255) carry_s = carry + tmp[255];
    __syncthreads();
  }
}

__global__ void k_scan3(int* __restrict__ rowptr, const int* __restrict__ partials,
                        int* __restrict__ cursor, int n, int Etot) {
  int gid = blockIdx.x * 256 + threadIdx.x;
  if (gid < n) {
    int v = rowptr[gid] + partials[blockIdx.x];
    rowptr[gid] = v;
    cursor[gid] = v;
  }
  if (gid == 0) rowptr[n] = Etot;
}

__global__ void k_scatter(const int* __restrict__ ei, int* __restrict__ cursor,
                          int* __restrict__ ssrc, int E, int Etot) {
  int e = blockIdx.x * 256 + threadIdx.x;
  if (e >= Etot) return;
  int src, dst;
  if (e < E) { src = ei[e]; dst = ei[E + e]; }
  else       { src = e - E; dst = e - E; }
  int pos = atomicAdd(&cursor[dst], 1);
  ssrc[pos] = src;
}

// ---------------- GEMM (r3-proven; RB adds fp32 per-column row-bias) ----------------
template<int K, bool RB>
__global__ __launch_bounds__(256) void k_gemm(
    const u16* __restrict__ A, const u16* __restrict__ Bl, const u16* __restrict__ Br,
    int NL, u16* __restrict__ Cl, u16* __restrict__ Cr, int M,
    const float* __restrict__ rbias) {
  __shared__ __align__(16) u16 Bt[64][K + 8];
  const int tid = threadIdx.x;
  const int m0 = blockIdx.x * 64;
  const int n0g = blockIdx.y * 64;
  const u16* B; u16* C; int col0;
  if (n0g < NL) { B = Bl; C = Cl; col0 = n0g; }
  else          { B = Br; C = Cr; col0 = n0g - NL; }

  for (int kb = 0; kb < K; kb += 4) {
    int k = kb + (tid >> 6);
    int nn = tid & 63;
    Bt[nn][k] = B[k * NL + col0 + nn];
  }
  __syncthreads();

  const int wave = tid >> 6, lane = tid & 63;
  const int wm = wave >> 1, wn = wave & 1;
  const int quad = lane >> 4, l16 = lane & 15;

  floatx4 acc[2][2] = {};
#pragma unroll
  for (int k0 = 0; k0 < K; k0 += 32) {
    short8 af[2], bfr[2];
#pragma unroll
    for (int mt = 0; mt < 2; mt++) {
      int row = m0 + wm * 32 + mt * 16 + l16;
      if (row > M - 1) row = M - 1;
      af[mt] = *(const short8*)(A + (size_t)row * K + k0 + quad * 8);
    }
#pragma unroll
    for (int nt = 0; nt < 2; nt++) {
      int nn = wn * 32 + nt * 16 + l16;
      bfr[nt] = *(const short8*)(&Bt[nn][k0 + quad * 8]);
    }
#pragma unroll
    for (int mt = 0; mt < 2; mt++)
#pragma unroll
      for (int nt = 0; nt < 2; nt++)
        acc[mt][nt] = __builtin_amdgcn_mfma_f32_16x16x32_bf16(af[mt], bfr[nt], acc[mt][nt], 0, 0, 0);
  }

#pragma unroll
  for (int mt = 0; mt < 2; mt++)
#pragma unroll
    for (int nt = 0; nt < 2; nt++) {
      float rb = 0.f;
      if (RB) rb = rbias[n0g + wn * 32 + nt * 16 + l16];
#pragma unroll
      for (int r = 0; r < 4; r++) {
        int row = m0 + wm * 32 + mt * 16 + quad * 4 + r;
        if (row < M) {
          int col = col0 + wn * 32 + nt * 16 + l16;
          C[(size_t)row * NL + col] = f2bf(acc[mt][nt][r] + rb);
        }
      }
    }
}

// ---------------- quarter-wave aggregation ----------------
// MODE 0 (HEADS=2): write bf16 helu with bias+elu.
// MODE 1 (HEADS=1): atomic-accumulate acc*inv into pooled[batch[node]][ch]
//                   (bias applied later in poolfinal; no h2 materialization).
template<int HEADS, int MODE>
__global__ __launch_bounds__(256) void k_agg(
    const u16* __restrict__ xl, const u16* __restrict__ xr,
    const u16* __restrict__ att, const u16* __restrict__ bias,
    const int* __restrict__ rowptr, const int* __restrict__ ssrc,
    const int* __restrict__ batch, float* __restrict__ pooled,
    void* __restrict__ outv, int n) {
  constexpr int F = HEADS * 128;
  constexpr int EPI = 4 / HEADS;
  int wave = threadIdx.x >> 6, lane = threadIdx.x & 63;
  int node = blockIdx.x * 4 + wave;
  if (node >= n) return;
  const int q = lane >> 4, l = lane & 15;
  const int eo   = (HEADS == 2) ? (q >> 1) : q;
  const int head = (HEADS == 2) ? (q & 1) : 0;
  const int ch0 = head * 128 + l * 8;

  float xrv[8], attv[8], acc[8];
  load8(xr + (size_t)node * F + ch0, xrv);
  load8(att + ch0, attv);
#pragma unroll
  for (int k = 0; k < 8; k++) acc[k] = 0.f;

  float l_run = 0.f;
  const int jb = rowptr[node], je = rowptr[node + 1];
  for (int j = jb; j < je; j += EPI) {
    int jj = j + eo;
    int src = ssrc[jj < je ? jj : (je - 1)];
    float xlv[8];
    load8(xl + (size_t)src * F + ch0, xlv);
    float s = 0.f;
#pragma unroll
    for (int k = 0; k < 8; k++) {
      float mm = xlv[k] + xrv[k];
      mm = mm > 0.f ? mm : NEG_SLOPE * mm;
      s += mm * attv[k];
    }
#pragma unroll
    for (int m = 1; m <= 8; m <<= 1) s += __shfl_xor(s, m, 64);  // intra-quarter
    float p = (jj < je) ? __expf(fminf(s, 80.f)) : 0.f;
    l_run += p;
#pragma unroll
    for (int k = 0; k < 8; k++) acc[k] += p * xlv[k];
  }

  // merge quarter-wave partials (same (node,head), different edges)
#pragma unroll
  for (int m = 16 * HEADS; m <= 32; m <<= 1) {
#pragma unroll
    for (int k = 0; k < 8; k++) acc[k] += __shfl_xor(acc[k], m, 64);
    l_run += __shfl_xor(l_run, m, 64);
  }

  if (lane < 16 * HEADS) {
    float inv = 1.f / (l_run + 1e-16f);
    if (MODE == 0) {
      short8 o;
#pragma unroll
      for (int k = 0; k < 8; k++) {
        float t = acc[k] * inv + bf2f(bias[ch0 + k]);
        t = t > 0.f ? t : (__expf(t) - 1.f);        // elu
        o[k] = (short)f2bf(t);
      }
      *(short8*)((u16*)outv + (size_t)node * F + ch0) = o;
    } else {
      float* pp = pooled + (size_t)batch[node] * F2 + ch0;
#pragma unroll
      for (int k = 0; k < 8; k++) atomicAdd(&pp[k], acc[k] * inv);
    }
  }
}

// ---------------- BN stats + fold into gemm2 weights ----------------
__global__ void k_stats(const u16* __restrict__ h, float* __restrict__ gsum,
                        float* __restrict__ gsumsq, int n) {
  int c = threadIdx.x;
  int r0 = blockIdx.x * 256;
  int r1 = min(r0 + 256, n);
  float s = 0.f, ss = 0.f;
  for (int r = r0; r < r1; ++r) {
    float v = bf2f(h[(size_t)r * F1 + c]);
    s += v; ss += v * v;
  }
  atomicAdd(&gsum[c], s);
  atomicAdd(&gsumsq[c], ss);
}

// h1b = a*helu + b; h1b@W = helu@(diag(a)W) + b@W. Scale W2 in place,
// emit rbias[256] fp32 (cols 0..127: b@Wl2, 128..255: b@Wr2).
__global__ void k_foldbn(const float* __restrict__ gsum, const float* __restrict__ gsumsq,
                         const u16* __restrict__ gamma, const u16* __restrict__ beta,
                         u16* __restrict__ Wl2, u16* __restrict__ Wr2,
                         float* __restrict__ rbias, float invn) {
  __shared__ float aS[256], bS[256];
  int t = threadIdx.x;   // 1 block x 256
  float mu = gsum[t] * invn;
  float var = gsumsq[t] * invn - mu * mu;
  float a = bf2f(gamma[t]) * rsqrtf(fmaxf(var, 0.f) + 1e-5f);
  float b = bf2f(beta[t]) - mu * a;
  aS[t] = a; bS[t] = b;
  __syncthreads();
  if (t < 128) {
    float sl = 0.f, sr = 0.f;
    for (int k = 0; k < 256; k++) {
      sl += bS[k] * bf2f(Wl2[k * 128 + t]);
      sr += bS[k] * bf2f(Wr2[k * 128 + t]);
    }
    rbias[t] = sl;
    rbias[128 + t] = sr;
  }
  __syncthreads();
  float ak = aS[t];
  for (int nn = 0; nn < 128; nn++) {
    Wl2[t * 128 + nn] = f2bf(ak * bf2f(Wl2[t * 128 + nn]));
    Wr2[t * 128 + nn] = f2bf(ak * bf2f(Wr2[t * 128 + nn]));
  }
}

// ---------------- final: mean + b2, then linear ----------------
__global__ void k_poolfinal(const float* __restrict__ pooled, const int* __restrict__ gcnt,
                            const u16* __restrict__ b2, const u16* __restrict__ Wlin,
                            const u16* __restrict__ blin, void* __restrict__ out,
                            const int* __restrict__ flag, int G) {
  int wave = threadIdx.x >> 6, lane = threadIdx.x & 63;
  int g = blockIdx.x * 4 + wave;
  if (g >= G) return;
  float cf = fmaxf((float)gcnt[g], 1.f);
  int ch = lane * 2;
  float2 pv = *(const float2*)(pooled + (size_t)g * F2 + ch);
  float c0 = pv.x / cf + bf2f(b2[ch]);
  float c1 = pv.y / cf + bf2f(b2[ch + 1]);
  float s0 = c0 * bf2f(Wlin[ch * 2 + 0]) + c1 * bf2f(Wlin[(ch + 1) * 2 + 0]);
  float s1 = c0 * bf2f(Wlin[ch * 2 + 1]) + c1 * bf2f(Wlin[(ch + 1) * 2 + 1]);
#pragma unroll
  for (int m = 1; m <= 32; m <<= 1) {
    s0 += __shfl_xor(s0, m, 64);
    s1 += __shfl_xor(s1, m, 64);
  }
  if (lane == 0) {
    float o0 = s0 + bf2f(blin[0]);
    float o1 = s1 + bf2f(blin[1]);
    if (*flag) {
      ((float*)out)[g * 2 + 0] = o0;
      ((float*)out)[g * 2 + 1] = o1;
    } else {
      ((u16*)out)[g * 2 + 0] = f2bf(o0);
      ((u16*)out)[g * 2 + 1] = f2bf(o1);
    }
  }
}

// ---------------- host ----------------
extern "C" void kernel_launch(void* const* d_in, const int* in_sizes, int n_in,
                              void* d_out, int out_size, void* d_ws, size_t ws_size,
                              hipStream_t stream) {
  const int* ei    = (const int*)d_in[1];
  const int* batch = (const int*)d_in[2];

  const int N = in_sizes[0] / DIN;
  const int E = in_sizes[1] / 2;
  const int G = out_size / 2;
  const int Etot = E + N;

  char* p = (char*)d_ws;
  auto alloc = [&](size_t bytes) {
    char* r = p;
    p += (bytes + 255) & ~(size_t)255;
    return r;
  };
  int*  flag     = (int*)alloc(256);
  // ---- single-memset zero region: hist | gsum | gsumsq | gcnt | pooled ----
  int*  hist     = (int*)alloc((size_t)N * 4);
  float* gsum    = (float*)alloc((size_t)F1 * 4);
  float* gsumsq  = (float*)alloc((size_t)F1 * 4);
  int*  gcnt     = (int*)alloc((size_t)G * 4);
  float* pooled  = (float*)alloc((size_t)G * F2 * 4);
  size_t zero_span = (size_t)((char*)pooled + (size_t)G * F2 * 4 - (char*)hist);
  // ---- rest ----
  int*  rowptr   = (int*)alloc((size_t)(N + 1) * 4);
  int*  cursor   = (int*)alloc((size_t)N * 4);
  int*  partials = (int*)alloc(4096);
  float* rbias   = (float*)alloc(256 * 4);
  int*  ssrc     = (int*)alloc((size_t)Etot * 4);
  u16*  xb       = (u16*)alloc((size_t)N * DIN * 2);
  u16*  pb       = (u16*)alloc(140000 * 2);
  u16*  regionA  = (u16*)alloc((size_t)N * F1 * 2);
  u16*  regionB  = (u16*)alloc((size_t)N * F1 * 2);
  u16*  regionC  = (u16*)alloc((size_t)N * F1 * 2);

  u16*  xl1  = regionA;
  u16*  xr1  = regionB;
  u16*  helu = regionC;                 // bf16 [N,F1] (gemm2 reads directly)
  u16*  xl2  = regionB;                 // bf16 [N,F2]  (B free after agg1)
  u16*  xr2  = regionB + (size_t)N * F2;

  // ---- dtype detect + canonicalize (one fused convert dispatch) ----
  k_detect<<<1, 64, 0, stream>>>((const u16*)d_in[0], flag);
  const int pidx[12] = {3, 4, 5, 6, 7, 8, 9, 10, 11, 12, 13, 14};
  PTab tab;
  int accum = 0;
  for (int i = 0; i < 12; i++) {
    tab.src[i] = d_in[pidx[i]];
    tab.off[i] = accum;
    accum += in_sizes[pidx[i]];
  }
  tab.off[12] = accum;
  {
    int n4 = in_sizes[0] / 4;
    int nxb = (n4 + 255) / 256;
    int npb = (accum + 255) / 256;
    k_convert_all<<<nxb + npb, 256, 0, stream>>>(d_in[0], xb, n4, nxb, tab, pb, accum, flag);
  }
  u16 *pWl1 = pb + tab.off[0], *pWr1 = pb + tab.off[1], *pAtt1 = pb + tab.off[2],
      *pB1 = pb + tab.off[3], *pGamma = pb + tab.off[4], *pBeta = pb + tab.off[5],
      *pWl2 = pb + tab.off[6], *pWr2 = pb + tab.off[7], *pAtt2 = pb + tab.off[8],
      *pB2 = pb + tab.off[9], *pWlin = pb + tab.off[10], *pBlin = pb + tab.off[11];

  hipMemsetAsync(hist, 0, zero_span, stream);

  const int eb = (Etot + 255) / 256;
  const int sb = (N + 255) / 256;

  k_hist<<<eb, 256, 0, stream>>>(ei, hist, batch, gcnt, E, Etot, N);
  k_scan1<<<sb, 256, 0, stream>>>(hist, rowptr, partials, N);
  k_scan2<<<1, 256, 0, stream>>>(partials, sb);
  k_scan3<<<sb, 256, 0, stream>>>(rowptr, partials, cursor, N, Etot);
  k_scatter<<<eb, 256, 0, stream>>>(ei, cursor, ssrc, E, Etot);

  dim3 g1((N + 63) / 64, (2 * F1) / 64);
  k_gemm<DIN, false><<<g1, 256, 0, stream>>>(xb, pWl1, pWr1, F1, xl1, xr1, N, nullptr);

  k_agg<2, 0><<<(N + 3) / 4, 256, 0, stream>>>(xl1, xr1, pAtt1, pB1, rowptr, ssrc,
                                               batch, nullptr, helu, N);

  k_stats<<<sb, 256, 0, stream>>>(helu, gsum, gsumsq, N);
  k_foldbn<<<1, 256, 0, stream>>>(gsum, gsumsq, pGamma, pBeta, pWl2, pWr2, rbias,
                                  1.0f / (float)N);

  dim3 g2((N + 63) / 64, (2 * F2) / 64);
  k_gemm<F1, true><<<g2, 256, 0, stream>>>(helu, pWl2, pWr2, F2, xl2, xr2, N, rbias);

  k_agg<1, 1><<<(N + 3) / 4, 256, 0, stream>>>(xl2, xr2, pAtt2, pB2, rowptr, ssrc,
                                               batch, pooled, nullptr, N);

  k_poolfinal<<<(G + 3) / 4, 256, 0, stream>>>(pooled, gcnt, pB2, pWlin, pBlin,
                                               d_out, flag, G);
}

// Round 8
// 550.075 us; speedup vs baseline: 1.3100x; 1.3100x over previous
//
#include <hip/hip_runtime.h>

// GATv2 2-layer GNN, MI355X. Inputs/out fp32 (proven r3); compute bf16.
// Round-8: REVERT r7's atomic pooling (device-scope atomics = memory-side
// RMW past non-coherent L2s: 6.4M atomics -> 200MB WRITE_SIZE, 246µs).
// agg2 writes h2 fp32 + b2 (r6-proven); poolfinal now 1 block/graph
// (4 waves, LDS merge) instead of 1 wave/graph. Fused converts kept.

#define DIN 128
#define F1 256   // H*DH layer 1
#define F2 128   // DOUT
#define NEG_SLOPE 0.2f

typedef unsigned short u16;
typedef __attribute__((ext_vector_type(8))) short short8;
typedef __attribute__((ext_vector_type(4))) float floatx4;

__device__ __forceinline__ float bf2f(u16 u) {
  return __uint_as_float(((unsigned int)u) << 16);
}
__device__ __forceinline__ u16 f2bf(float f) {   // round-to-nearest-even
  unsigned int x = __float_as_uint(f);
  return (u16)((x + 0x7fffu + ((x >> 16) & 1u)) >> 16);
}
__device__ __forceinline__ void load8(const u16* p, float (&f)[8]) {
  short8 v = *(const short8*)p;
#pragma unroll
  for (int k = 0; k < 8; k++) f[k] = bf2f((u16)v[k]);
}

// ---------------- dtype detection (flag=1: fp32 inputs; 0: bf16) ----------------
__global__ void k_detect(const u16* __restrict__ x, int* __restrict__ flag) {
  int lane = threadIdx.x;   // 1 block x 64 threads
  int cnt = 0;
#pragma unroll
  for (int i = 0; i < 2; ++i) {
    u16 v = x[2 * (lane + 64 * i)];
    int e = (v >> 7) & 0xFF;
    if (e >= 115 && e <= 130) cnt++;
  }
#pragma unroll
  for (int m = 1; m <= 32; m <<= 1) cnt += __shfl_xor(cnt, m, 64);
  if (lane == 0) *flag = (cnt < 64) ? 1 : 0;
}

// fused convert: blocks [0,nxb) do x (4 elems/thread); rest do params (1/thread)
struct PTab { const void* src[12]; int off[13]; };
__global__ void k_convert_all(const void* __restrict__ xsrc, u16* __restrict__ xb,
                              int n4, int nxb, PTab t, u16* __restrict__ pb,
                              int ptotal, const int* __restrict__ flag) {
  if ((int)blockIdx.x < nxb) {
    int i = blockIdx.x * 256 + threadIdx.x;
    if (i >= n4) return;
    if (*flag) {
      float4 a = ((const float4*)xsrc)[i];
      ushort4 o;
      o.x = f2bf(a.x); o.y = f2bf(a.y); o.z = f2bf(a.z); o.w = f2bf(a.w);
      ((ushort4*)xb)[i] = o;
    } else {
      ((ulong1*)xb)[i] = ((const ulong1*)xsrc)[i];
    }
  } else {
    int i = (blockIdx.x - nxb) * 256 + threadIdx.x;
    if (i >= ptotal) return;
    int s = 0;
#pragma unroll
    for (int k = 1; k < 12; k++) s += (i >= t.off[k]);
    int local = i - t.off[s];
    const void* sp = t.src[s];
    pb[i] = (*flag) ? f2bf(((const float*)sp)[local]) : ((const u16*)sp)[local];
  }
}

// ---------------- CSR build ----------------
__global__ void k_hist(const int* __restrict__ ei, int* __restrict__ hist,
                       const int* __restrict__ batch, int* __restrict__ gcnt,
                       int E, int Etot, int N) {
  int e = blockIdx.x * 256 + threadIdx.x;
  if (e >= Etot) return;
  int dst = (e < E) ? ei[E + e] : (e - E);
  atomicAdd(&hist[dst], 1);
  if (e < N) atomicAdd(&gcnt[batch[e]], 1);
}

__global__ void k_scan1(const int* __restrict__ in, int* __restrict__ out,
                        int* __restrict__ partials, int n) {
  __shared__ int tmp[256];
  int t = threadIdx.x;
  int gid = blockIdx.x * 256 + t;
  int v = (gid < n) ? in[gid] : 0;
  tmp[t] = v;
  __syncthreads();
  for (int off = 1; off < 256; off <<= 1) {
    int add = (t >= off) ? tmp[t - off] : 0;
    __syncthreads();
    tmp[t] += add;
    __syncthreads();
  }
  if (gid < n) out[gid] = tmp[t] - v;
  if (t == 255) partials[blockIdx.x] = tmp[255];
}

__global__ void k_scan2(int* __restrict__ partials, int nb) {
  __shared__ int tmp[256];
  __shared__ int carry_s;
  int t = threadIdx.x;
  if (t == 0) carry_s = 0;
  __syncthreads();
  for (int base = 0; base < nb; base += 256) {
    int idx = base + t;
    int v = (idx < nb) ? partials[idx] : 0;
    tmp[t] = v;
    __syncthreads();
    for (int off = 1; off < 256; off <<= 1) {
      int add = (t >= off) ? tmp[t - off] : 0;
      __syncthreads();
      tmp[t] += add;
      __syncthreads();
    }
    int carry = carry_s;
    if (idx < nb) partials[idx] = tmp[t] - v + carry;
    __syncthreads();
    if (t == 255) carry_s = carry + tmp[255];
    __syncthreads();
  }
}

__global__ void k_scan3(int* __restrict__ rowptr, const int* __restrict__ partials,
                        int* __restrict__ cursor, int n, int Etot) {
  int gid = blockIdx.x * 256 + threadIdx.x;
  if (gid < n) {
    int v = rowptr[gid] + partials[blockIdx.x];
    rowptr[gid] = v;
    cursor[gid] = v;
  }
  if (gid == 0) rowptr[n] = Etot;
}

__global__ void k_scatter(const int* __restrict__ ei, int* __restrict__ cursor,
                          int* __restrict__ ssrc, int E, int Etot) {
  int e = blockIdx.x * 256 + threadIdx.x;
  if (e >= Etot) return;
  int src, dst;
  if (e < E) { src = ei[e]; dst = ei[E + e]; }
  else       { src = e - E; dst = e - E; }
  int pos = atomicAdd(&cursor[dst], 1);
  ssrc[pos] = src;
}

// ---------------- GEMM (r3-proven; RB adds fp32 per-column row-bias) ----------------
template<int K, bool RB>
__global__ __launch_bounds__(256) void k_gemm(
    const u16* __restrict__ A, const u16* __restrict__ Bl, const u16* __restrict__ Br,
    int NL, u16* __restrict__ Cl, u16* __restrict__ Cr, int M,
    const float* __restrict__ rbias) {
  __shared__ __align__(16) u16 Bt[64][K + 8];
  const int tid = threadIdx.x;
  const int m0 = blockIdx.x * 64;
  const int n0g = blockIdx.y * 64;
  const u16* B; u16* C; int col0;
  if (n0g < NL) { B = Bl; C = Cl; col0 = n0g; }
  else          { B = Br; C = Cr; col0 = n0g - NL; }

  for (int kb = 0; kb < K; kb += 4) {
    int k = kb + (tid >> 6);
    int nn = tid & 63;
    Bt[nn][k] = B[k * NL + col0 + nn];
  }
  __syncthreads();

  const int wave = tid >> 6, lane = tid & 63;
  const int wm = wave >> 1, wn = wave & 1;
  const int quad = lane >> 4, l16 = lane & 15;

  floatx4 acc[2][2] = {};
#pragma unroll
  for (int k0 = 0; k0 < K; k0 += 32) {
    short8 af[2], bfr[2];
#pragma unroll
    for (int mt = 0; mt < 2; mt++) {
      int row = m0 + wm * 32 + mt * 16 + l16;
      if (row > M - 1) row = M - 1;
      af[mt] = *(const short8*)(A + (size_t)row * K + k0 + quad * 8);
    }
#pragma unroll
    for (int nt = 0; nt < 2; nt++) {
      int nn = wn * 32 + nt * 16 + l16;
      bfr[nt] = *(const short8*)(&Bt[nn][k0 + quad * 8]);
    }
#pragma unroll
    for (int mt = 0; mt < 2; mt++)
#pragma unroll
      for (int nt = 0; nt < 2; nt++)
        acc[mt][nt] = __builtin_amdgcn_mfma_f32_16x16x32_bf16(af[mt], bfr[nt], acc[mt][nt], 0, 0, 0);
  }

#pragma unroll
  for (int mt = 0; mt < 2; mt++)
#pragma unroll
    for (int nt = 0; nt < 2; nt++) {
      float rb = 0.f;
      if (RB) rb = rbias[n0g + wn * 32 + nt * 16 + l16];
#pragma unroll
      for (int r = 0; r < 4; r++) {
        int row = m0 + wm * 32 + mt * 16 + quad * 4 + r;
        if (row < M) {
          int col = col0 + wn * 32 + nt * 16 + l16;
          C[(size_t)row * NL + col] = f2bf(acc[mt][nt][r] + rb);
        }
      }
    }
}

// ---------------- quarter-wave aggregation (r6-proven) ----------------
// MODE 0 (HEADS=2): write bf16 helu with bias+elu.
// MODE 1 (HEADS=1): write fp32 h2 with bias (no elu).
template<int HEADS, int MODE>
__global__ __launch_bounds__(256) void k_agg(
    const u16* __restrict__ xl, const u16* __restrict__ xr,
    const u16* __restrict__ att, const u16* __restrict__ bias,
    const int* __restrict__ rowptr, const int* __restrict__ ssrc,
    void* __restrict__ outv, int n) {
  constexpr int F = HEADS * 128;
  constexpr int EPI = 4 / HEADS;
  int wave = threadIdx.x >> 6, lane = threadIdx.x & 63;
  int node = blockIdx.x * 4 + wave;
  if (node >= n) return;
  const int q = lane >> 4, l = lane & 15;
  const int eo   = (HEADS == 2) ? (q >> 1) : q;
  const int head = (HEADS == 2) ? (q & 1) : 0;
  const int ch0 = head * 128 + l * 8;

  float xrv[8], attv[8], acc[8];
  load8(xr + (size_t)node * F + ch0, xrv);
  load8(att + ch0, attv);
#pragma unroll
  for (int k = 0; k < 8; k++) acc[k] = 0.f;

  float l_run = 0.f;
  const int jb = rowptr[node], je = rowptr[node + 1];
  for (int j = jb; j < je; j += EPI) {
    int jj = j + eo;
    int src = ssrc[jj < je ? jj : (je - 1)];
    float xlv[8];
    load8(xl + (size_t)src * F + ch0, xlv);
    float s = 0.f;
#pragma unroll
    for (int k = 0; k < 8; k++) {
      float mm = xlv[k] + xrv[k];
      mm = mm > 0.f ? mm : NEG_SLOPE * mm;
      s += mm * attv[k];
    }
#pragma unroll
    for (int m = 1; m <= 8; m <<= 1) s += __shfl_xor(s, m, 64);  // intra-quarter
    float p = (jj < je) ? __expf(fminf(s, 80.f)) : 0.f;
    l_run += p;
#pragma unroll
    for (int k = 0; k < 8; k++) acc[k] += p * xlv[k];
  }

  // merge quarter-wave partials (same (node,head), different edges)
#pragma unroll
  for (int m = 16 * HEADS; m <= 32; m <<= 1) {
#pragma unroll
    for (int k = 0; k < 8; k++) acc[k] += __shfl_xor(acc[k], m, 64);
    l_run += __shfl_xor(l_run, m, 64);
  }

  if (lane < 16 * HEADS) {
    float inv = 1.f / (l_run + 1e-16f);
    if (MODE == 0) {
      short8 o;
#pragma unroll
      for (int k = 0; k < 8; k++) {
        float t = acc[k] * inv + bf2f(bias[ch0 + k]);
        t = t > 0.f ? t : (__expf(t) - 1.f);        // elu
        o[k] = (short)f2bf(t);
      }
      *(short8*)((u16*)outv + (size_t)node * F + ch0) = o;
    } else {
      float v[8];
#pragma unroll
      for (int k = 0; k < 8; k++) v[k] = acc[k] * inv + bf2f(bias[ch0 + k]);
      float* op = (float*)outv + (size_t)node * F + ch0;
      *(float4*)op = make_float4(v[0], v[1], v[2], v[3]);
      *(float4*)(op + 4) = make_float4(v[4], v[5], v[6], v[7]);
    }
  }
}

// ---------------- BN stats + fold into gemm2 weights ----------------
__global__ void k_stats(const u16* __restrict__ h, float* __restrict__ gsum,
                        float* __restrict__ gsumsq, int n) {
  int c = threadIdx.x;
  int r0 = blockIdx.x * 256;
  int r1 = min(r0 + 256, n);
  float s = 0.f, ss = 0.f;
  for (int r = r0; r < r1; ++r) {
    float v = bf2f(h[(size_t)r * F1 + c]);
    s += v; ss += v * v;
  }
  atomicAdd(&gsum[c], s);
  atomicAdd(&gsumsq[c], ss);
}

// h1b = a*helu + b; h1b@W = helu@(diag(a)W) + b@W. Scale W2 in place,
// emit rbias[256] fp32 (cols 0..127: b@Wl2, 128..255: b@Wr2).
__global__ void k_foldbn(const float* __restrict__ gsum, const float* __restrict__ gsumsq,
                         const u16* __restrict__ gamma, const u16* __restrict__ beta,
                         u16* __restrict__ Wl2, u16* __restrict__ Wr2,
                         float* __restrict__ rbias, float invn) {
  __shared__ float aS[256], bS[256];
  int t = threadIdx.x;   // 1 block x 256
  float mu = gsum[t] * invn;
  float var = gsumsq[t] * invn - mu * mu;
  float a = bf2f(gamma[t]) * rsqrtf(fmaxf(var, 0.f) + 1e-5f);
  float b = bf2f(beta[t]) - mu * a;
  aS[t] = a; bS[t] = b;
  __syncthreads();
  if (t < 128) {
    float sl = 0.f, sr = 0.f;
    for (int k = 0; k < 256; k++) {
      sl += bS[k] * bf2f(Wl2[k * 128 + t]);
      sr += bS[k] * bf2f(Wr2[k * 128 + t]);
    }
    rbias[t] = sl;
    rbias[128 + t] = sr;
  }
  __syncthreads();
  float ak = aS[t];
  for (int nn = 0; nn < 128; nn++) {
    Wl2[t * 128 + nn] = f2bf(ak * bf2f(Wl2[t * 128 + nn]));
    Wr2[t * 128 + nn] = f2bf(ak * bf2f(Wr2[t * 128 + nn]));
  }
}

// ---------------- pool + final linear: 1 block (4 waves) per graph ----------------
__global__ __launch_bounds__(256) void k_poolfinal(
    const float* __restrict__ h2, const int* __restrict__ grptr,
    const u16* __restrict__ Wlin, const u16* __restrict__ blin,
    void* __restrict__ out, const int* __restrict__ flag, int G, int N) {
  __shared__ float sm[4][128];
  int g = blockIdx.x;
  int wave = threadIdx.x >> 6, lane = threadIdx.x & 63;
  int jb = grptr[g];
  int je = (g == G - 1) ? N : grptr[g + 1];
  int ch = lane * 2;
  float c0 = 0.f, c1 = 0.f;
  for (int r = jb + wave; r < je; r += 4) {
    float2 v = *(const float2*)(h2 + (size_t)r * F2 + ch);
    c0 += v.x; c1 += v.y;
  }
  sm[wave][ch] = c0;
  sm[wave][ch + 1] = c1;
  __syncthreads();
  if (wave == 0) {
    c0 = sm[0][ch] + sm[1][ch] + sm[2][ch] + sm[3][ch];
    c1 = sm[0][ch + 1] + sm[1][ch + 1] + sm[2][ch + 1] + sm[3][ch + 1];
    float cf = fmaxf((float)(je - jb), 1.f);
    c0 /= cf; c1 /= cf;
    float s0 = c0 * bf2f(Wlin[ch * 2 + 0]) + c1 * bf2f(Wlin[(ch + 1) * 2 + 0]);
    float s1 = c0 * bf2f(Wlin[ch * 2 + 1]) + c1 * bf2f(Wlin[(ch + 1) * 2 + 1]);
#pragma unroll
    for (int m = 1; m <= 32; m <<= 1) {
      s0 += __shfl_xor(s0, m, 64);
      s1 += __shfl_xor(s1, m, 64);
    }
    if (lane == 0) {
      float o0 = s0 + bf2f(blin[0]);
      float o1 = s1 + bf2f(blin[1]);
      if (*flag) {
        ((float*)out)[g * 2 + 0] = o0;
        ((float*)out)[g * 2 + 1] = o1;
      } else {
        ((u16*)out)[g * 2 + 0] = f2bf(o0);
        ((u16*)out)[g * 2 + 1] = f2bf(o1);
      }
    }
  }
}

// ---------------- host ----------------
extern "C" void kernel_launch(void* const* d_in, const int* in_sizes, int n_in,
                              void* d_out, int out_size, void* d_ws, size_t ws_size,
                              hipStream_t stream) {
  const int* ei    = (const int*)d_in[1];
  const int* batch = (const int*)d_in[2];

  const int N = in_sizes[0] / DIN;
  const int E = in_sizes[1] / 2;
  const int G = out_size / 2;
  const int Etot = E + N;

  char* p = (char*)d_ws;
  auto alloc = [&](size_t bytes) {
    char* r = p;
    p += (bytes + 255) & ~(size_t)255;
    return r;
  };
  int*  flag     = (int*)alloc(256);
  // ---- single-memset zero region: hist | gsum | gsumsq | gcnt ----
  int*  hist     = (int*)alloc((size_t)N * 4);
  float* gsum    = (float*)alloc((size_t)F1 * 4);
  float* gsumsq  = (float*)alloc((size_t)F1 * 4);
  int*  gcnt     = (int*)alloc((size_t)G * 4);
  size_t zero_span = (size_t)((char*)gcnt + (size_t)G * 4 - (char*)hist);
  // ---- rest ----
  int*  rowptr   = (int*)alloc((size_t)(N + 1) * 4);
  int*  cursor   = (int*)alloc((size_t)N * 4);
  int*  partials = (int*)alloc(4096);
  float* rbias   = (float*)alloc(256 * 4);
  int*  ssrc     = (int*)alloc((size_t)Etot * 4);
  u16*  xb       = (u16*)alloc((size_t)N * DIN * 2);
  u16*  pb       = (u16*)alloc(140000 * 2);
  u16*  regionA  = (u16*)alloc((size_t)N * F1 * 2);
  u16*  regionB  = (u16*)alloc((size_t)N * F1 * 2);
  u16*  regionC  = (u16*)alloc((size_t)N * F1 * 2);

  u16*  xl1  = regionA;
  u16*  xr1  = regionB;
  u16*  helu = regionC;                 // bf16 [N,F1] (gemm2 reads directly)
  u16*  xl2  = regionB;                 // bf16 [N,F2]  (B free after agg1)
  u16*  xr2  = regionB + (size_t)N * F2;
  float* h2  = (float*)regionA;         // fp32 [N,F2]  (A free after gemm2)

  // ---- dtype detect + canonicalize (one fused convert dispatch) ----
  k_detect<<<1, 64, 0, stream>>>((const u16*)d_in[0], flag);
  const int pidx[12] = {3, 4, 5, 6, 7, 8, 9, 10, 11, 12, 13, 14};
  PTab tab;
  int accum = 0;
  for (int i = 0; i < 12; i++) {
    tab.src[i] = d_in[pidx[i]];
    tab.off[i] = accum;
    accum += in_sizes[pidx[i]];
  }
  tab.off[12] = accum;
  {
    int n4 = in_sizes[0] / 4;
    int nxb = (n4 + 255) / 256;
    int npb = (accum + 255) / 256;
    k_convert_all<<<nxb + npb, 256, 0, stream>>>(d_in[0], xb, n4, nxb, tab, pb, accum, flag);
  }
  u16 *pWl1 = pb + tab.off[0], *pWr1 = pb + tab.off[1], *pAtt1 = pb + tab.off[2],
      *pB1 = pb + tab.off[3], *pGamma = pb + tab.off[4], *pBeta = pb + tab.off[5],
      *pWl2 = pb + tab.off[6], *pWr2 = pb + tab.off[7], *pAtt2 = pb + tab.off[8],
      *pB2 = pb + tab.off[9], *pWlin = pb + tab.off[10], *pBlin = pb + tab.off[11];

  hipMemsetAsync(hist, 0, zero_span, stream);

  const int eb = (Etot + 255) / 256;
  const int sb = (N + 255) / 256;

  k_hist<<<eb, 256, 0, stream>>>(ei, hist, batch, gcnt, E, Etot, N);
  k_scan1<<<sb, 256, 0, stream>>>(hist, rowptr, partials, N);
  k_scan2<<<1, 256, 0, stream>>>(partials, sb);
  k_scan3<<<sb, 256, 0, stream>>>(rowptr, partials, cursor, N, Etot);
  k_scatter<<<eb, 256, 0, stream>>>(ei, cursor, ssrc, E, Etot);

  dim3 g1((N + 63) / 64, (2 * F1) / 64);
  k_gemm<DIN, false><<<g1, 256, 0, stream>>>(xb, pWl1, pWr1, F1, xl1, xr1, N, nullptr);

  k_agg<2, 0><<<(N + 3) / 4, 256, 0, stream>>>(xl1, xr1, pAtt1, pB1, rowptr, ssrc, helu, N);

  k_stats<<<sb, 256, 0, stream>>>(helu, gsum, gsumsq, N);
  k_foldbn<<<1, 256, 0, stream>>>(gsum, gsumsq, pGamma, pBeta, pWl2, pWr2, rbias,
                                  1.0f / (float)N);

  dim3 g2((N + 63) / 64, (2 * F2) / 64);
  k_gemm<F1, true><<<g2, 256, 0, stream>>>(helu, pWl2, pWr2, F2, xl2, xr2, N, rbias);

  k_agg<1, 1><<<(N + 3) / 4, 256, 0, stream>>>(xl2, xr2, pAtt2, pB2, rowptr, ssrc, h2, N);

  k_scan2<<<1, 256, 0, stream>>>(gcnt, G);   // exclusive scan -> grptr
  k_poolfinal<<<G, 256, 0, stream>>>(h2, gcnt, pWlin, pBlin, d_out, flag, G, N);
}

// Round 9
// 539.048 us; speedup vs baseline: 1.3368x; 1.0205x over previous
//
#include <hip/hip_runtime.h>

// GATv2 2-layer GNN, MI355X. Inputs/out fp32 (proven r3); compute bf16.
// Round-9: (1) LDS-free GEMM — weights pre-transposed once into ws (extra
// blocks in fused convert kernel), B fragments vector-loaded from L2-resident
// global; no staging loop, no barrier. (2) foldbn parallelized to 128 blocks
// on transposed W2. (3) k_detect deleted (convert blocks self-detect; block 0
// persists flag for poolfinal). agg kernels r6-proven, untouched.

#define DIN 128
#define F1 256   // H*DH layer 1
#define F2 128   // DOUT
#define NEG_SLOPE 0.2f

typedef unsigned short u16;
typedef __attribute__((ext_vector_type(8))) short short8;
typedef __attribute__((ext_vector_type(4))) float floatx4;

__device__ __forceinline__ float bf2f(u16 u) {
  return __uint_as_float(((unsigned int)u) << 16);
}
__device__ __forceinline__ u16 f2bf(float f) {   // round-to-nearest-even
  unsigned int x = __float_as_uint(f);
  return (u16)((x + 0x7fffu + ((x >> 16) & 1u)) >> 16);
}
__device__ __forceinline__ void load8(const u16* p, float (&f)[8]) {
  short8 v = *(const short8*)p;
#pragma unroll
  for (int k = 0; k < 8; k++) f[k] = bf2f((u16)v[k]);
}

// ---------------- fused convert + transpose + self-detect ----------------
// flag=1: fp32 inputs; 0: bf16. Each block self-detects from x's first 256B.
struct PTab { const void* src[8]; int off[9]; };
__global__ __launch_bounds__(256) void k_convert_all(
    const void* __restrict__ xsrc, u16* __restrict__ xb, int n4, int nxb,
    PTab t, u16* __restrict__ pb, int ptotal, int npb,
    const void* __restrict__ Wl1s, const void* __restrict__ Wr1s,
    const void* __restrict__ Wl2s, const void* __restrict__ Wr2s,
    u16* __restrict__ Wl1t, u16* __restrict__ Wr1t,
    u16* __restrict__ Wl2t, u16* __restrict__ Wr2t, int* __restrict__ flag) {
  __shared__ int flagS;
  int tid = threadIdx.x;
  if (tid < 64) {
    int cnt = 0;
#pragma unroll
    for (int i = 0; i < 2; ++i) {
      u16 v = ((const u16*)xsrc)[2 * (tid + 64 * i)];  // even u16: fp32 low halves
      int e = (v >> 7) & 0xFF;
      if (e >= 115 && e <= 130) cnt++;                 // bf16 N(0,1) exponent range
    }
#pragma unroll
    for (int m = 1; m <= 32; m <<= 1) cnt += __shfl_xor(cnt, m, 64);
    if (tid == 0) flagS = (cnt < 64) ? 1 : 0;
  }
  __syncthreads();
  const int fl = flagS;
  if (blockIdx.x == 0 && tid == 0) *flag = fl;   // persist for poolfinal

  int b = blockIdx.x;
  if (b < nxb) {                                  // x convert, 4 elems/thread
    int i = b * 256 + tid;
    if (i >= n4) return;
    if (fl) {
      float4 a = ((const float4*)xsrc)[i];
      ushort4 o;
      o.x = f2bf(a.x); o.y = f2bf(a.y); o.z = f2bf(a.z); o.w = f2bf(a.w);
      ((ushort4*)xb)[i] = o;
    } else {
      ((ulong1*)xb)[i] = ((const ulong1*)xsrc)[i];
    }
    return;
  }
  b -= nxb;
  if (b < npb) {                                  // small params (no W's)
    int i = b * 256 + tid;
    if (i >= ptotal) return;
    int s = 0;
#pragma unroll
    for (int k = 1; k < 8; k++) s += (i >= t.off[k]);
    int local = i - t.off[s];
    pb[i] = fl ? f2bf(((const float*)t.src[s])[local]) : ((const u16*)t.src[s])[local];
    return;
  }
  b -= npb;
  // weight transposes: W[K,NL] -> Wt[NL,K]; 4 segs x 128 blocks (32768 elems each)
  int seg = b >> 7;
  int i = (b & 127) * 256 + tid;
  const void* s; u16* d; int NL, sh;
  if      (seg == 0) { s = Wl1s; d = Wl1t; NL = 256; sh = 7; }
  else if (seg == 1) { s = Wr1s; d = Wr1t; NL = 256; sh = 7; }
  else if (seg == 2) { s = Wl2s; d = Wl2t; NL = 128; sh = 8; }
  else               { s = Wr2s; d = Wr2t; NL = 128; sh = 8; }
  int n = i >> sh, k = i & ((1 << sh) - 1);
  int si = k * NL + n;
  d[i] = fl ? f2bf(((const float*)s)[si]) : ((const u16*)s)[si];
}

// ---------------- CSR build ----------------
__global__ void k_hist(const int* __restrict__ ei, int* __restrict__ hist,
                       const int* __restrict__ batch, int* __restrict__ gcnt,
                       int E, int Etot, int N) {
  int e = blockIdx.x * 256 + threadIdx.x;
  if (e >= Etot) return;
  int dst = (e < E) ? ei[E + e] : (e - E);
  atomicAdd(&hist[dst], 1);
  if (e < N) atomicAdd(&gcnt[batch[e]], 1);
}

__global__ void k_scan1(const int* __restrict__ in, int* __restrict__ out,
                        int* __restrict__ partials, int n) {
  __shared__ int tmp[256];
  int t = threadIdx.x;
  int gid = blockIdx.x * 256 + t;
  int v = (gid < n) ? in[gid] : 0;
  tmp[t] = v;
  __syncthreads();
  for (int off = 1; off < 256; off <<= 1) {
    int add = (t >= off) ? tmp[t - off] : 0;
    __syncthreads();
    tmp[t] += add;
    __syncthreads();
  }
  if (gid < n) out[gid] = tmp[t] - v;
  if (t == 255) partials[blockIdx.x] = tmp[255];
}

__global__ void k_scan2(int* __restrict__ partials, int nb) {
  __shared__ int tmp[256];
  __shared__ int carry_s;
  int t = threadIdx.x;
  if (t == 0) carry_s = 0;
  __syncthreads();
  for (int base = 0; base < nb; base += 256) {
    int idx = base + t;
    int v = (idx < nb) ? partials[idx] : 0;
    tmp[t] = v;
    __syncthreads();
    for (int off = 1; off < 256; off <<= 1) {
      int add = (t >= off) ? tmp[t - off] : 0;
      __syncthreads();
      tmp[t] += add;
      __syncthreads();
    }
    int carry = carry_s;
    if (idx < nb) partials[idx] = tmp[t] - v + carry;
    __syncthreads();
    if (t == 255) carry_s = carry + tmp[255];
    __syncthreads();
  }
}

__global__ void k_scan3(int* __restrict__ rowptr, const int* __restrict__ partials,
                        int* __restrict__ cursor, int n, int Etot) {
  int gid = blockIdx.x * 256 + threadIdx.x;
  if (gid < n) {
    int v = rowptr[gid] + partials[blockIdx.x];
    rowptr[gid] = v;
    cursor[gid] = v;
  }
  if (gid == 0) rowptr[n] = Etot;
}

__global__ void k_scatter(const int* __restrict__ ei, int* __restrict__ cursor,
                          int* __restrict__ ssrc, int E, int Etot) {
  int e = blockIdx.x * 256 + threadIdx.x;
  if (e >= Etot) return;
  int src, dst;
  if (e < E) { src = ei[e]; dst = ei[E + e]; }
  else       { src = e - E; dst = e - E; }
  int pos = atomicAdd(&cursor[dst], 1);
  ssrc[pos] = src;
}

// ---------------- GEMM: LDS-free, B pre-transposed Bt[NL][K] ----------------
template<int K, bool RB>
__global__ __launch_bounds__(256) void k_gemm(
    const u16* __restrict__ A, const u16* __restrict__ Blt, const u16* __restrict__ Brt,
    int NL, u16* __restrict__ Cl, u16* __restrict__ Cr, int M,
    const float* __restrict__ rbias) {
  const int tid = threadIdx.x;
  const int m0 = blockIdx.x * 64;
  const int n0g = blockIdx.y * 64;
  const u16* Bt; u16* C; int col0;
  if (n0g < NL) { Bt = Blt; C = Cl; col0 = n0g; }
  else          { Bt = Brt; C = Cr; col0 = n0g - NL; }

  const int wave = tid >> 6, lane = tid & 63;
  const int wm = wave >> 1, wn = wave & 1;
  const int quad = lane >> 4, l16 = lane & 15;

  floatx4 acc[2][2] = {};
#pragma unroll
  for (int k0 = 0; k0 < K; k0 += 32) {
    short8 af[2], bfr[2];
#pragma unroll
    for (int mt = 0; mt < 2; mt++) {
      int row = m0 + wm * 32 + mt * 16 + l16;
      if (row > M - 1) row = M - 1;
      af[mt] = *(const short8*)(A + (size_t)row * K + k0 + quad * 8);
    }
#pragma unroll
    for (int nt = 0; nt < 2; nt++) {
      int nn = col0 + wn * 32 + nt * 16 + l16;
      bfr[nt] = *(const short8*)(Bt + (size_t)nn * K + k0 + quad * 8);
    }
#pragma unroll
    for (int mt = 0; mt < 2; mt++)
#pragma unroll
      for (int nt = 0; nt < 2; nt++)
        acc[mt][nt] = __builtin_amdgcn_mfma_f32_16x16x32_bf16(af[mt], bfr[nt], acc[mt][nt], 0, 0, 0);
  }

#pragma unroll
  for (int mt = 0; mt < 2; mt++)
#pragma unroll
    for (int nt = 0; nt < 2; nt++) {
      float rb = 0.f;
      if (RB) rb = rbias[n0g + wn * 32 + nt * 16 + l16];
#pragma unroll
      for (int r = 0; r < 4; r++) {
        int row = m0 + wm * 32 + mt * 16 + quad * 4 + r;
        if (row < M) {
          int col = col0 + wn * 32 + nt * 16 + l16;
          C[(size_t)row * NL + col] = f2bf(acc[mt][nt][r] + rb);
        }
      }
    }
}

// ---------------- quarter-wave aggregation (r6-proven) ----------------
// MODE 0 (HEADS=2): write bf16 helu with bias+elu.
// MODE 1 (HEADS=1): write fp32 h2 with bias (no elu).
template<int HEADS, int MODE>
__global__ __launch_bounds__(256) void k_agg(
    const u16* __restrict__ xl, const u16* __restrict__ xr,
    const u16* __restrict__ att, const u16* __restrict__ bias,
    const int* __restrict__ rowptr, const int* __restrict__ ssrc,
    void* __restrict__ outv, int n) {
  constexpr int F = HEADS * 128;
  constexpr int EPI = 4 / HEADS;
  int wave = threadIdx.x >> 6, lane = threadIdx.x & 63;
  int node = blockIdx.x * 4 + wave;
  if (node >= n) return;
  const int q = lane >> 4, l = lane & 15;
  const int eo   = (HEADS == 2) ? (q >> 1) : q;
  const int head = (HEADS == 2) ? (q & 1) : 0;
  const int ch0 = head * 128 + l * 8;

  float xrv[8], attv[8], acc[8];
  load8(xr + (size_t)node * F + ch0, xrv);
  load8(att + ch0, attv);
#pragma unroll
  for (int k = 0; k < 8; k++) acc[k] = 0.f;

  float l_run = 0.f;
  const int jb = rowptr[node], je = rowptr[node + 1];
  for (int j = jb; j < je; j += EPI) {
    int jj = j + eo;
    int src = ssrc[jj < je ? jj : (je - 1)];
    float xlv[8];
    load8(xl + (size_t)src * F + ch0, xlv);
    float s = 0.f;
#pragma unroll
    for (int k = 0; k < 8; k++) {
      float mm = xlv[k] + xrv[k];
      mm = mm > 0.f ? mm : NEG_SLOPE * mm;
      s += mm * attv[k];
    }
#pragma unroll
    for (int m = 1; m <= 8; m <<= 1) s += __shfl_xor(s, m, 64);  // intra-quarter
    float p = (jj < je) ? __expf(fminf(s, 80.f)) : 0.f;
    l_run += p;
#pragma unroll
    for (int k = 0; k < 8; k++) acc[k] += p * xlv[k];
  }

#pragma unroll
  for (int m = 16 * HEADS; m <= 32; m <<= 1) {
#pragma unroll
    for (int k = 0; k < 8; k++) acc[k] += __shfl_xor(acc[k], m, 64);
    l_run += __shfl_xor(l_run, m, 64);
  }

  if (lane < 16 * HEADS) {
    float inv = 1.f / (l_run + 1e-16f);
    if (MODE == 0) {
      short8 o;
#pragma unroll
      for (int k = 0; k < 8; k++) {
        float t = acc[k] * inv + bf2f(bias[ch0 + k]);
        t = t > 0.f ? t : (__expf(t) - 1.f);        // elu
        o[k] = (short)f2bf(t);
      }
      *(short8*)((u16*)outv + (size_t)node * F + ch0) = o;
    } else {
      float v[8];
#pragma unroll
      for (int k = 0; k < 8; k++) v[k] = acc[k] * inv + bf2f(bias[ch0 + k]);
      float* op = (float*)outv + (size_t)node * F + ch0;
      *(float4*)op = make_float4(v[0], v[1], v[2], v[3]);
      *(float4*)(op + 4) = make_float4(v[4], v[5], v[6], v[7]);
    }
  }
}

// ---------------- BN stats + fold into transposed gemm2 weights ----------------
__global__ void k_stats(const u16* __restrict__ h, float* __restrict__ gsum,
                        float* __restrict__ gsumsq, int n) {
  int c = threadIdx.x;
  int r0 = blockIdx.x * 256;
  int r1 = min(r0 + 256, n);
  float s = 0.f, ss = 0.f;
  for (int r = r0; r < r1; ++r) {
    float v = bf2f(h[(size_t)r * F1 + c]);
    s += v; ss += v * v;
  }
  atomicAdd(&gsum[c], s);
  atomicAdd(&gsumsq[c], ss);
}

// h1b = a*helu + b; h1b@W = helu@(diag(a)W) + b@W. Wt[n][k] layout:
// block n scales row n of Wl2t/Wr2t by a[k] and reduces rbias[n] = sum b[k]*W.
__global__ __launch_bounds__(256) void k_foldbn(
    const float* __restrict__ gsum, const float* __restrict__ gsumsq,
    const u16* __restrict__ gamma, const u16* __restrict__ beta,
    u16* __restrict__ Wl2t, u16* __restrict__ Wr2t,
    float* __restrict__ rbias, float invn) {
  __shared__ float red[8];
  int t = threadIdx.x, n = blockIdx.x;   // 128 blocks x 256 threads
  float mu = gsum[t] * invn;
  float var = gsumsq[t] * invn - mu * mu;
  float a = bf2f(gamma[t]) * rsqrtf(fmaxf(var, 0.f) + 1e-5f);
  float b = bf2f(beta[t]) - mu * a;
  float wl = bf2f(Wl2t[n * 256 + t]);
  float wr = bf2f(Wr2t[n * 256 + t]);
  float sl = b * wl, sr = b * wr;
  Wl2t[n * 256 + t] = f2bf(a * wl);
  Wr2t[n * 256 + t] = f2bf(a * wr);
#pragma unroll
  for (int m = 1; m <= 32; m <<= 1) {
    sl += __shfl_xor(sl, m, 64);
    sr += __shfl_xor(sr, m, 64);
  }
  int wave = t >> 6, lane = t & 63;
  if (lane == 0) { red[wave] = sl; red[4 + wave] = sr; }
  __syncthreads();
  if (t == 0) rbias[n] = red[0] + red[1] + red[2] + red[3];
  if (t == 1) rbias[128 + n] = red[4] + red[5] + red[6] + red[7];
}

// ---------------- pool + final linear: 1 block (4 waves) per graph ----------------
__global__ __launch_bounds__(256) void k_poolfinal(
    const float* __restrict__ h2, const int* __restrict__ grptr,
    const u16* __restrict__ Wlin, const u16* __restrict__ blin,
    void* __restrict__ out, const int* __restrict__ flag, int G, int N) {
  __shared__ float sm[4][128];
  int g = blockIdx.x;
  int wave = threadIdx.x >> 6, lane = threadIdx.x & 63;
  int jb = grptr[g];
  int je = (g == G - 1) ? N : grptr[g + 1];
  int ch = lane * 2;
  float c0 = 0.f, c1 = 0.f;
  for (int r = jb + wave; r < je; r += 4) {
    float2 v = *(const float2*)(h2 + (size_t)r * F2 + ch);
    c0 += v.x; c1 += v.y;
  }
  sm[wave][ch] = c0;
  sm[wave][ch + 1] = c1;
  __syncthreads();
  if (wave == 0) {
    c0 = sm[0][ch] + sm[1][ch] + sm[2][ch] + sm[3][ch];
    c1 = sm[0][ch + 1] + sm[1][ch + 1] + sm[2][ch + 1] + sm[3][ch + 1];
    float cf = fmaxf((float)(je - jb), 1.f);
    c0 /= cf; c1 /= cf;
    float s0 = c0 * bf2f(Wlin[ch * 2 + 0]) + c1 * bf2f(Wlin[(ch + 1) * 2 + 0]);
    float s1 = c0 * bf2f(Wlin[ch * 2 + 1]) + c1 * bf2f(Wlin[(ch + 1) * 2 + 1]);
#pragma unroll
    for (int m = 1; m <= 32; m <<= 1) {
      s0 += __shfl_xor(s0, m, 64);
      s1 += __shfl_xor(s1, m, 64);
    }
    if (lane == 0) {
      float o0 = s0 + bf2f(blin[0]);
      float o1 = s1 + bf2f(blin[1]);
      if (*flag) {
        ((float*)out)[g * 2 + 0] = o0;
        ((float*)out)[g * 2 + 1] = o1;
      } else {
        ((u16*)out)[g * 2 + 0] = f2bf(o0);
        ((u16*)out)[g * 2 + 1] = f2bf(o1);
      }
    }
  }
}

// ---------------- host ----------------
extern "C" void kernel_launch(void* const* d_in, const int* in_sizes, int n_in,
                              void* d_out, int out_size, void* d_ws, size_t ws_size,
                              hipStream_t stream) {
  const int* ei    = (const int*)d_in[1];
  const int* batch = (const int*)d_in[2];

  const int N = in_sizes[0] / DIN;
  const int E = in_sizes[1] / 2;
  const int G = out_size / 2;
  const int Etot = E + N;

  char* p = (char*)d_ws;
  auto alloc = [&](size_t bytes) {
    char* r = p;
    p += (bytes + 255) & ~(size_t)255;
    return r;
  };
  int*  flag     = (int*)alloc(256);
  // ---- single-memset zero region: hist | gsum | gsumsq | gcnt ----
  int*  hist     = (int*)alloc((size_t)N * 4);
  float* gsum    = (float*)alloc((size_t)F1 * 4);
  float* gsumsq  = (float*)alloc((size_t)F1 * 4);
  int*  gcnt     = (int*)alloc((size_t)G * 4);
  size_t zero_span = (size_t)((char*)gcnt + (size_t)G * 4 - (char*)hist);
  // ---- rest ----
  int*  rowptr   = (int*)alloc((size_t)(N + 1) * 4);
  int*  cursor   = (int*)alloc((size_t)N * 4);
  int*  partials = (int*)alloc(4096);
  float* rbias   = (float*)alloc(256 * 4);
  int*  ssrc     = (int*)alloc((size_t)Etot * 4);
  u16*  xb       = (u16*)alloc((size_t)N * DIN * 2);
  u16*  pb       = (u16*)alloc(4096);
  u16*  Wl1t     = (u16*)alloc(DIN * F1 * 2);   // [256][128]
  u16*  Wr1t     = (u16*)alloc(DIN * F1 * 2);
  u16*  Wl2t     = (u16*)alloc(F1 * F2 * 2);    // [128][256]
  u16*  Wr2t     = (u16*)alloc(F1 * F2 * 2);
  u16*  regionA  = (u16*)alloc((size_t)N * F1 * 2);
  u16*  regionB  = (u16*)alloc((size_t)N * F1 * 2);
  u16*  regionC  = (u16*)alloc((size_t)N * F1 * 2);

  u16*  xl1  = regionA;
  u16*  xr1  = regionB;
  u16*  helu = regionC;                 // bf16 [N,F1] (gemm2 reads directly)
  u16*  xl2  = regionB;                 // bf16 [N,F2]  (B free after agg1)
  u16*  xr2  = regionB + (size_t)N * F2;
  float* h2  = (float*)regionA;         // fp32 [N,F2]  (A free after gemm2)

  // ---- fused convert (+transpose, +self-detect) ----
  const int pidx[8] = {5, 6, 7, 8, 11, 12, 13, 14};  // att1,b1,gamma,beta,att2,b2,Wlin,blin
  PTab tab;
  int accum = 0;
  for (int i = 0; i < 8; i++) {
    tab.src[i] = d_in[pidx[i]];
    tab.off[i] = accum;
    accum += in_sizes[pidx[i]];
  }
  tab.off[8] = accum;
  int n4 = in_sizes[0] / 4;
  int nxb = (n4 + 255) / 256;
  int npb = (accum + 255) / 256;
  k_convert_all<<<nxb + npb + 512, 256, 0, stream>>>(
      d_in[0], xb, n4, nxb, tab, pb, accum, npb,
      d_in[3], d_in[4], d_in[9], d_in[10], Wl1t, Wr1t, Wl2t, Wr2t, flag);
  u16 *pAtt1 = pb + tab.off[0], *pB1 = pb + tab.off[1], *pGamma = pb + tab.off[2],
      *pBeta = pb + tab.off[3], *pAtt2 = pb + tab.off[4], *pB2 = pb + tab.off[5],
      *pWlin = pb + tab.off[6], *pBlin = pb + tab.off[7];

  hipMemsetAsync(hist, 0, zero_span, stream);

  const int eb = (Etot + 255) / 256;
  const int sb = (N + 255) / 256;

  k_hist<<<eb, 256, 0, stream>>>(ei, hist, batch, gcnt, E, Etot, N);
  k_scan1<<<sb, 256, 0, stream>>>(hist, rowptr, partials, N);
  k_scan2<<<1, 256, 0, stream>>>(partials, sb);
  k_scan3<<<sb, 256, 0, stream>>>(rowptr, partials, cursor, N, Etot);
  k_scatter<<<eb, 256, 0, stream>>>(ei, cursor, ssrc, E, Etot);

  dim3 g1((N + 63) / 64, (2 * F1) / 64);
  k_gemm<DIN, false><<<g1, 256, 0, stream>>>(xb, Wl1t, Wr1t, F1, xl1, xr1, N, nullptr);

  k_agg<2, 0><<<(N + 3) / 4, 256, 0, stream>>>(xl1, xr1, pAtt1, pB1, rowptr, ssrc, helu, N);

  k_stats<<<sb, 256, 0, stream>>>(helu, gsum, gsumsq, N);
  k_foldbn<<<128, 256, 0, stream>>>(gsum, gsumsq, pGamma, pBeta, Wl2t, Wr2t, rbias,
                                    1.0f / (float)N);

  dim3 g2((N + 63) / 64, (2 * F2) / 64);
  k_gemm<F1, true><<<g2, 256, 0, stream>>>(helu, Wl2t, Wr2t, F2, xl2, xr2, N, rbias);

  k_agg<1, 1><<<(N + 3) / 4, 256, 0, stream>>>(xl2, xr2, pAtt2, pB2, rowptr, ssrc, h2, N);

  k_scan2<<<1, 256, 0, stream>>>(gcnt, G);   // exclusive scan -> grptr
  k_poolfinal<<<G, 256, 0, stream>>>(h2, gcnt, pWlin, pBlin, d_out, flag, G, N);
}

// Round 10
// 455.195 us; speedup vs baseline: 1.5830x; 1.1842x over previous
//
#include <hip/hip_runtime.h>

// GATv2 2-layer GNN, MI355X. Inputs/out fp32 (proven r3); compute bf16.
// Round-10: dispatch diet 16 -> 11. (1) zeroing folded into convert_all;
// (2) 3-dispatch scan -> 1 single-pass decoupled-lookback scan;
// (3) poolfinal binary-searches sorted batch (gcnt/scan deleted);
// (4) k_stats vectorized (short8, LDS merge). Heavy kernels r9-proven.

#define DIN 128
#define F1 256   // H*DH layer 1
#define F2 128   // DOUT
#define NEG_SLOPE 0.2f

typedef unsigned short u16;
typedef __attribute__((ext_vector_type(8))) short short8;
typedef __attribute__((ext_vector_type(4))) float floatx4;

__device__ __forceinline__ float bf2f(u16 u) {
  return __uint_as_float(((unsigned int)u) << 16);
}
__device__ __forceinline__ u16 f2bf(float f) {   // round-to-nearest-even
  unsigned int x = __float_as_uint(f);
  return (u16)((x + 0x7fffu + ((x >> 16) & 1u)) >> 16);
}
__device__ __forceinline__ void load8(const u16* p, float (&f)[8]) {
  short8 v = *(const short8*)p;
#pragma unroll
  for (int k = 0; k < 8; k++) f[k] = bf2f((u16)v[k]);
}

// ---------------- fused convert + transpose + zero + self-detect ----------------
struct PTab { const void* src[8]; int off[9]; };
__global__ __launch_bounds__(256) void k_convert_all(
    const void* __restrict__ xsrc, u16* __restrict__ xb, int n4, int nxb,
    PTab t, u16* __restrict__ pb, int ptotal, int npb,
    const void* __restrict__ Wl1s, const void* __restrict__ Wr1s,
    const void* __restrict__ Wl2s, const void* __restrict__ Wr2s,
    u16* __restrict__ Wl1t, u16* __restrict__ Wr1t,
    u16* __restrict__ Wl2t, u16* __restrict__ Wr2t,
    int* __restrict__ zbase, int zn, int* __restrict__ flag) {
  __shared__ int flagS;
  int tid = threadIdx.x;
  if (tid < 64) {
    int cnt = 0;
#pragma unroll
    for (int i = 0; i < 2; ++i) {
      u16 v = ((const u16*)xsrc)[2 * (tid + 64 * i)];  // even u16: fp32 low halves
      int e = (v >> 7) & 0xFF;
      if (e >= 115 && e <= 130) cnt++;                 // bf16 N(0,1) exponent range
    }
#pragma unroll
    for (int m = 1; m <= 32; m <<= 1) cnt += __shfl_xor(cnt, m, 64);
    if (tid == 0) flagS = (cnt < 64) ? 1 : 0;
  }
  __syncthreads();
  const int fl = flagS;
  if (blockIdx.x == 0 && tid == 0) *flag = fl;   // persist for poolfinal

  int b = blockIdx.x;
  if (b < nxb) {                                  // x convert, 4 elems/thread
    int i = b * 256 + tid;
    if (i >= n4) return;
    if (fl) {
      float4 a = ((const float4*)xsrc)[i];
      ushort4 o;
      o.x = f2bf(a.x); o.y = f2bf(a.y); o.z = f2bf(a.z); o.w = f2bf(a.w);
      ((ushort4*)xb)[i] = o;
    } else {
      ((ulong1*)xb)[i] = ((const ulong1*)xsrc)[i];
    }
    return;
  }
  b -= nxb;
  if (b < npb) {                                  // small params (no W's)
    int i = b * 256 + tid;
    if (i >= ptotal) return;
    int s = 0;
#pragma unroll
    for (int k = 1; k < 8; k++) s += (i >= t.off[k]);
    int local = i - t.off[s];
    pb[i] = fl ? f2bf(((const float*)t.src[s])[local]) : ((const u16*)t.src[s])[local];
    return;
  }
  b -= npb;
  if (b < 512) {
    // weight transposes: W[K,NL] -> Wt[NL,K]; 4 segs x 128 blocks
    int seg = b >> 7;
    int i = (b & 127) * 256 + tid;
    const void* s; u16* d; int NL, sh;
    if      (seg == 0) { s = Wl1s; d = Wl1t; NL = 256; sh = 7; }
    else if (seg == 1) { s = Wr1s; d = Wr1t; NL = 256; sh = 7; }
    else if (seg == 2) { s = Wl2s; d = Wl2t; NL = 128; sh = 8; }
    else               { s = Wr2s; d = Wr2t; NL = 128; sh = 8; }
    int n = i >> sh, k = i & ((1 << sh) - 1);
    int si = k * NL + n;
    d[i] = fl ? f2bf(((const float*)s)[si]) : ((const u16*)s)[si];
    return;
  }
  b -= 512;
  int i = b * 256 + tid;                          // zero region (ints)
  if (i < zn) zbase[i] = 0;
}

// ---------------- CSR build ----------------
__global__ void k_hist(const int* __restrict__ ei, int* __restrict__ hist,
                       int E, int Etot) {
  int e = blockIdx.x * 256 + threadIdx.x;
  if (e >= Etot) return;
  int dst = (e < E) ? ei[E + e] : (e - E);
  atomicAdd(&hist[dst], 1);
}

// single-pass decoupled-lookback exclusive scan; writes rowptr & cursor
__global__ void k_scan(const int* __restrict__ hist, int* __restrict__ rowptr,
                       int* __restrict__ cursor, unsigned long long* __restrict__ pstate,
                       int* __restrict__ ctr, int n, int Etot) {
  __shared__ int tmp[256];
  __shared__ int bidS, offS;
  int t = threadIdx.x;
  if (t == 0) bidS = atomicAdd(ctr, 1);
  __syncthreads();
  int bid = bidS;
  int gid = bid * 256 + t;
  int v = (gid < n) ? hist[gid] : 0;
  tmp[t] = v;
  __syncthreads();
  for (int off = 1; off < 256; off <<= 1) {
    int add = (t >= off) ? tmp[t - off] : 0;
    __syncthreads();
    tmp[t] += add;
    __syncthreads();
  }
  if (t == 0) {
    int total = tmp[255];
    unsigned long long st =
        ((unsigned long long)(bid == 0 ? 2 : 1) << 32) | (unsigned)total;
    atomicExch(&pstate[bid], st);
    int off = 0;
    if (bid > 0) {
      int b = bid - 1;
      while (true) {
        unsigned long long s;
        do { s = atomicAdd(&pstate[b], 0ULL); } while ((s >> 32) == 0);
        off += (int)(unsigned)s;
        if ((s >> 32) == 2) break;
        b--;
      }
      atomicExch(&pstate[bid],
                 ((unsigned long long)2 << 32) | (unsigned)(off + total));
    }
    offS = off;
  }
  __syncthreads();
  int off = offS;
  if (gid < n) {
    int ex = off + tmp[t] - v;
    rowptr[gid] = ex;
    cursor[gid] = ex;
  }
  if (gid == 0) rowptr[n] = Etot;
}

__global__ void k_scatter(const int* __restrict__ ei, int* __restrict__ cursor,
                          int* __restrict__ ssrc, int E, int Etot) {
  int e = blockIdx.x * 256 + threadIdx.x;
  if (e >= Etot) return;
  int src, dst;
  if (e < E) { src = ei[e]; dst = ei[E + e]; }
  else       { src = e - E; dst = e - E; }
  int pos = atomicAdd(&cursor[dst], 1);
  ssrc[pos] = src;
}

// ---------------- GEMM: LDS-free, B pre-transposed Bt[NL][K] (r9-proven) ----------------
template<int K, bool RB>
__global__ __launch_bounds__(256) void k_gemm(
    const u16* __restrict__ A, const u16* __restrict__ Blt, const u16* __restrict__ Brt,
    int NL, u16* __restrict__ Cl, u16* __restrict__ Cr, int M,
    const float* __restrict__ rbias) {
  const int tid = threadIdx.x;
  const int m0 = blockIdx.x * 64;
  const int n0g = blockIdx.y * 64;
  const u16* Bt; u16* C; int col0;
  if (n0g < NL) { Bt = Blt; C = Cl; col0 = n0g; }
  else          { Bt = Brt; C = Cr; col0 = n0g - NL; }

  const int wave = tid >> 6, lane = tid & 63;
  const int wm = wave >> 1, wn = wave & 1;
  const int quad = lane >> 4, l16 = lane & 15;

  floatx4 acc[2][2] = {};
#pragma unroll
  for (int k0 = 0; k0 < K; k0 += 32) {
    short8 af[2], bfr[2];
#pragma unroll
    for (int mt = 0; mt < 2; mt++) {
      int row = m0 + wm * 32 + mt * 16 + l16;
      if (row > M - 1) row = M - 1;
      af[mt] = *(const short8*)(A + (size_t)row * K + k0 + quad * 8);
    }
#pragma unroll
    for (int nt = 0; nt < 2; nt++) {
      int nn = col0 + wn * 32 + nt * 16 + l16;
      bfr[nt] = *(const short8*)(Bt + (size_t)nn * K + k0 + quad * 8);
    }
#pragma unroll
    for (int mt = 0; mt < 2; mt++)
#pragma unroll
      for (int nt = 0; nt < 2; nt++)
        acc[mt][nt] = __builtin_amdgcn_mfma_f32_16x16x32_bf16(af[mt], bfr[nt], acc[mt][nt], 0, 0, 0);
  }

#pragma unroll
  for (int mt = 0; mt < 2; mt++)
#pragma unroll
    for (int nt = 0; nt < 2; nt++) {
      float rb = 0.f;
      if (RB) rb = rbias[n0g + wn * 32 + nt * 16 + l16];
#pragma unroll
      for (int r = 0; r < 4; r++) {
        int row = m0 + wm * 32 + mt * 16 + quad * 4 + r;
        if (row < M) {
          int col = col0 + wn * 32 + nt * 16 + l16;
          C[(size_t)row * NL + col] = f2bf(acc[mt][nt][r] + rb);
        }
      }
    }
}

// ---------------- quarter-wave aggregation (r6-proven) ----------------
template<int HEADS, int MODE>
__global__ __launch_bounds__(256) void k_agg(
    const u16* __restrict__ xl, const u16* __restrict__ xr,
    const u16* __restrict__ att, const u16* __restrict__ bias,
    const int* __restrict__ rowptr, const int* __restrict__ ssrc,
    void* __restrict__ outv, int n) {
  constexpr int F = HEADS * 128;
  constexpr int EPI = 4 / HEADS;
  int wave = threadIdx.x >> 6, lane = threadIdx.x & 63;
  int node = blockIdx.x * 4 + wave;
  if (node >= n) return;
  const int q = lane >> 4, l = lane & 15;
  const int eo   = (HEADS == 2) ? (q >> 1) : q;
  const int head = (HEADS == 2) ? (q & 1) : 0;
  const int ch0 = head * 128 + l * 8;

  float xrv[8], attv[8], acc[8];
  load8(xr + (size_t)node * F + ch0, xrv);
  load8(att + ch0, attv);
#pragma unroll
  for (int k = 0; k < 8; k++) acc[k] = 0.f;

  float l_run = 0.f;
  const int jb = rowptr[node], je = rowptr[node + 1];
  for (int j = jb; j < je; j += EPI) {
    int jj = j + eo;
    int src = ssrc[jj < je ? jj : (je - 1)];
    float xlv[8];
    load8(xl + (size_t)src * F + ch0, xlv);
    float s = 0.f;
#pragma unroll
    for (int k = 0; k < 8; k++) {
      float mm = xlv[k] + xrv[k];
      mm = mm > 0.f ? mm : NEG_SLOPE * mm;
      s += mm * attv[k];
    }
#pragma unroll
    for (int m = 1; m <= 8; m <<= 1) s += __shfl_xor(s, m, 64);  // intra-quarter
    float p = (jj < je) ? __expf(fminf(s, 80.f)) : 0.f;
    l_run += p;
#pragma unroll
    for (int k = 0; k < 8; k++) acc[k] += p * xlv[k];
  }

#pragma unroll
  for (int m = 16 * HEADS; m <= 32; m <<= 1) {
#pragma unroll
    for (int k = 0; k < 8; k++) acc[k] += __shfl_xor(acc[k], m, 64);
    l_run += __shfl_xor(l_run, m, 64);
  }

  if (lane < 16 * HEADS) {
    float inv = 1.f / (l_run + 1e-16f);
    if (MODE == 0) {
      short8 o;
#pragma unroll
      for (int k = 0; k < 8; k++) {
        float t = acc[k] * inv + bf2f(bias[ch0 + k]);
        t = t > 0.f ? t : (__expf(t) - 1.f);        // elu
        o[k] = (short)f2bf(t);
      }
      *(short8*)((u16*)outv + (size_t)node * F + ch0) = o;
    } else {
      float v[8];
#pragma unroll
      for (int k = 0; k < 8; k++) v[k] = acc[k] * inv + bf2f(bias[ch0 + k]);
      float* op = (float*)outv + (size_t)node * F + ch0;
      *(float4*)op = make_float4(v[0], v[1], v[2], v[3]);
      *(float4*)(op + 4) = make_float4(v[4], v[5], v[6], v[7]);
    }
  }
}

// ---------------- BN stats (vectorized) + fold into transposed gemm2 weights ----------------
// block: 8 row-lanes x 32 ch-lanes; thread accumulates 8 channels via short8.
__global__ __launch_bounds__(256) void k_stats(
    const u16* __restrict__ h, float* __restrict__ gsum,
    float* __restrict__ gsumsq, int n) {
  __shared__ float smS[8][256], smQ[8][256];
  int t = threadIdx.x;
  int rg = t >> 5, cl = t & 31;
  int ch0 = cl * 8;
  float s[8] = {}, q[8] = {};
  for (int r = blockIdx.x * 8 + rg; r < n; r += gridDim.x * 8) {
    float v[8];
    load8(h + (size_t)r * F1 + ch0, v);
#pragma unroll
    for (int k = 0; k < 8; k++) { s[k] += v[k]; q[k] += v[k] * v[k]; }
  }
#pragma unroll
  for (int k = 0; k < 8; k++) { smS[rg][ch0 + k] = s[k]; smQ[rg][ch0 + k] = q[k]; }
  __syncthreads();
  float ts = 0.f, tq = 0.f;
#pragma unroll
  for (int g = 0; g < 8; g++) { ts += smS[g][t]; tq += smQ[g][t]; }
  atomicAdd(&gsum[t], ts);
  atomicAdd(&gsumsq[t], tq);
}

__global__ __launch_bounds__(256) void k_foldbn(
    const float* __restrict__ gsum, const float* __restrict__ gsumsq,
    const u16* __restrict__ gamma, const u16* __restrict__ beta,
    u16* __restrict__ Wl2t, u16* __restrict__ Wr2t,
    float* __restrict__ rbias, float invn) {
  __shared__ float red[8];
  int t = threadIdx.x, n = blockIdx.x;   // 128 blocks x 256 threads
  float mu = gsum[t] * invn;
  float var = gsumsq[t] * invn - mu * mu;
  float a = bf2f(gamma[t]) * rsqrtf(fmaxf(var, 0.f) + 1e-5f);
  float b = bf2f(beta[t]) - mu * a;
  float wl = bf2f(Wl2t[n * 256 + t]);
  float wr = bf2f(Wr2t[n * 256 + t]);
  float sl = b * wl, sr = b * wr;
  Wl2t[n * 256 + t] = f2bf(a * wl);
  Wr2t[n * 256 + t] = f2bf(a * wr);
#pragma unroll
  for (int m = 1; m <= 32; m <<= 1) {
    sl += __shfl_xor(sl, m, 64);
    sr += __shfl_xor(sr, m, 64);
  }
  int wave = t >> 6, lane = t & 63;
  if (lane == 0) { red[wave] = sl; red[4 + wave] = sr; }
  __syncthreads();
  if (t == 0) rbias[n] = red[0] + red[1] + red[2] + red[3];
  if (t == 1) rbias[128 + n] = red[4] + red[5] + red[6] + red[7];
}

// ---------------- pool + final linear: 1 block/graph, binary-search bounds ----------------
__device__ __forceinline__ int lowerb(const int* __restrict__ a, int n, int key) {
  int lo = 0, hi = n;
  while (lo < hi) { int m = (lo + hi) >> 1; if (a[m] < key) lo = m + 1; else hi = m; }
  return lo;
}

__global__ __launch_bounds__(256) void k_poolfinal(
    const float* __restrict__ h2, const int* __restrict__ batch,
    const u16* __restrict__ Wlin, const u16* __restrict__ blin,
    void* __restrict__ out, const int* __restrict__ flag, int G, int N) {
  __shared__ float sm[4][128];
  int g = blockIdx.x;
  int wave = threadIdx.x >> 6, lane = threadIdx.x & 63;
  int jb = lowerb(batch, N, g);
  int je = lowerb(batch, N, g + 1);
  int ch = lane * 2;
  float c0 = 0.f, c1 = 0.f;
  for (int r = jb + wave; r < je; r += 4) {
    float2 v = *(const float2*)(h2 + (size_t)r * F2 + ch);
    c0 += v.x; c1 += v.y;
  }
  sm[wave][ch] = c0;
  sm[wave][ch + 1] = c1;
  __syncthreads();
  if (wave == 0) {
    c0 = sm[0][ch] + sm[1][ch] + sm[2][ch] + sm[3][ch];
    c1 = sm[0][ch + 1] + sm[1][ch + 1] + sm[2][ch + 1] + sm[3][ch + 1];
    float cf = fmaxf((float)(je - jb), 1.f);
    c0 /= cf; c1 /= cf;
    float s0 = c0 * bf2f(Wlin[ch * 2 + 0]) + c1 * bf2f(Wlin[(ch + 1) * 2 + 0]);
    float s1 = c0 * bf2f(Wlin[ch * 2 + 1]) + c1 * bf2f(Wlin[(ch + 1) * 2 + 1]);
#pragma unroll
    for (int m = 1; m <= 32; m <<= 1) {
      s0 += __shfl_xor(s0, m, 64);
      s1 += __shfl_xor(s1, m, 64);
    }
    if (lane == 0) {
      float o0 = s0 + bf2f(blin[0]);
      float o1 = s1 + bf2f(blin[1]);
      if (*flag) {
        ((float*)out)[g * 2 + 0] = o0;
        ((float*)out)[g * 2 + 1] = o1;
      } else {
        ((u16*)out)[g * 2 + 0] = f2bf(o0);
        ((u16*)out)[g * 2 + 1] = f2bf(o1);
      }
    }
  }
}

// ---------------- host ----------------
extern "C" void kernel_launch(void* const* d_in, const int* in_sizes, int n_in,
                              void* d_out, int out_size, void* d_ws, size_t ws_size,
                              hipStream_t stream) {
  const int* ei    = (const int*)d_in[1];
  const int* batch = (const int*)d_in[2];

  const int N = in_sizes[0] / DIN;
  const int E = in_sizes[1] / 2;
  const int G = out_size / 2;
  const int Etot = E + N;

  char* p = (char*)d_ws;
  auto alloc = [&](size_t bytes) {
    char* r = p;
    p += (bytes + 255) & ~(size_t)255;
    return r;
  };
  int*  flag     = (int*)alloc(256);
  // ---- zero region (zeroed by convert_all): hist | gsum | gsumsq | pstate | ctr ----
  int*  hist     = (int*)alloc((size_t)N * 4);
  float* gsum    = (float*)alloc(1024);
  float* gsumsq  = (float*)alloc(1024);
  unsigned long long* pstate = (unsigned long long*)alloc(2048);
  int*  ctr      = (int*)alloc(256);
  int   zn       = (int)(((char*)ctr + 256) - (char*)hist) / 4;
  // ---- rest ----
  int*  rowptr   = (int*)alloc((size_t)(N + 1) * 4);
  int*  cursor   = (int*)alloc((size_t)N * 4);
  float* rbias   = (float*)alloc(256 * 4);
  int*  ssrc     = (int*)alloc((size_t)Etot * 4);
  u16*  xb       = (u16*)alloc((size_t)N * DIN * 2);
  u16*  pb       = (u16*)alloc(4096);
  u16*  Wl1t     = (u16*)alloc(DIN * F1 * 2);   // [256][128]
  u16*  Wr1t     = (u16*)alloc(DIN * F1 * 2);
  u16*  Wl2t     = (u16*)alloc(F1 * F2 * 2);    // [128][256]
  u16*  Wr2t     = (u16*)alloc(F1 * F2 * 2);
  u16*  regionA  = (u16*)alloc((size_t)N * F1 * 2);
  u16*  regionB  = (u16*)alloc((size_t)N * F1 * 2);
  u16*  regionC  = (u16*)alloc((size_t)N * F1 * 2);

  u16*  xl1  = regionA;
  u16*  xr1  = regionB;
  u16*  helu = regionC;                 // bf16 [N,F1] (gemm2 reads directly)
  u16*  xl2  = regionB;                 // bf16 [N,F2]  (B free after agg1)
  u16*  xr2  = regionB + (size_t)N * F2;
  float* h2  = (float*)regionA;         // fp32 [N,F2]  (A free after gemm2)

  // ---- fused convert (+transpose, +zero, +self-detect) ----
  const int pidx[8] = {5, 6, 7, 8, 11, 12, 13, 14};  // att1,b1,gamma,beta,att2,b2,Wlin,blin
  PTab tab;
  int accum = 0;
  for (int i = 0; i < 8; i++) {
    tab.src[i] = d_in[pidx[i]];
    tab.off[i] = accum;
    accum += in_sizes[pidx[i]];
  }
  tab.off[8] = accum;
  int n4 = in_sizes[0] / 4;
  int nxb = (n4 + 255) / 256;
  int npb = (accum + 255) / 256;
  int nzb = (zn + 255) / 256;
  k_convert_all<<<nxb + npb + 512 + nzb, 256, 0, stream>>>(
      d_in[0], xb, n4, nxb, tab, pb, accum, npb,
      d_in[3], d_in[4], d_in[9], d_in[10], Wl1t, Wr1t, Wl2t, Wr2t,
      hist, zn, flag);
  u16 *pAtt1 = pb + tab.off[0], *pB1 = pb + tab.off[1], *pGamma = pb + tab.off[2],
      *pBeta = pb + tab.off[3], *pAtt2 = pb + tab.off[4], *pB2 = pb + tab.off[5],
      *pWlin = pb + tab.off[6], *pBlin = pb + tab.off[7];

  const int eb = (Etot + 255) / 256;
  const int sb = (N + 255) / 256;

  k_hist<<<eb, 256, 0, stream>>>(ei, hist, E, Etot);
  k_scan<<<sb, 256, 0, stream>>>(hist, rowptr, cursor, pstate, ctr, N, Etot);
  k_scatter<<<eb, 256, 0, stream>>>(ei, cursor, ssrc, E, Etot);

  dim3 g1((N + 63) / 64, (2 * F1) / 64);
  k_gemm<DIN, false><<<g1, 256, 0, stream>>>(xb, Wl1t, Wr1t, F1, xl1, xr1, N, nullptr);

  k_agg<2, 0><<<(N + 3) / 4, 256, 0, stream>>>(xl1, xr1, pAtt1, pB1, rowptr, ssrc, helu, N);

  k_stats<<<256, 256, 0, stream>>>(helu, gsum, gsumsq, N);
  k_foldbn<<<128, 256, 0, stream>>>(gsum, gsumsq, pGamma, pBeta, Wl2t, Wr2t, rbias,
                                    1.0f / (float)N);

  dim3 g2((N + 63) / 64, (2 * F2) / 64);
  k_gemm<F1, true><<<g2, 256, 0, stream>>>(helu, Wl2t, Wr2t, F2, xl2, xr2, N, rbias);

  k_agg<1, 1><<<(N + 3) / 4, 256, 0, stream>>>(xl2, xr2, pAtt2, pB2, rowptr, ssrc, h2, N);

  k_poolfinal<<<G, 256, 0, stream>>>(h2, batch, pWlin, pBlin, d_out, flag, G, N);
}